// Round 5
// baseline (24200.259 us; speedup 1.0000x reference)
//
#include <hip/hip_runtime.h>
#include <hip/hip_bf16.h>

#define HDIM 1024
#define VDIM 512
#define TLEN 256
#define BATCH 256
#define FPDIM 2048
#define H3 3072

typedef __hip_bfloat16 bf16;
typedef __attribute__((ext_vector_type(8))) short s8v;    // 8 bf16 (4 VGPRs)
typedef __attribute__((ext_vector_type(4))) float f4v;    // MFMA C/D

__device__ __forceinline__ f4v mfma_bf16(s8v a, s8v b, f4v c) {
  return __builtin_amdgcn_mfma_f32_16x16x32_bf16(a, b, c, 0, 0, 0);
}
__device__ __forceinline__ s8v ld8(const bf16* p) { return *(const s8v*)p; }
__device__ __forceinline__ float sigf(float x) { return 1.f / (1.f + expf(-x)); }
__device__ __forceinline__ short f2bs(float f) {           // fp32->bf16 RNE
  union { float f; unsigned u; } c; c.f = f;
  unsigned u = c.u + 0x7fff + ((c.u >> 16) & 1);
  return (short)(u >> 16);
}

// ====== one-time: fp32 [N,1024] -> bf16 MFMA A/B-frag blob ======
// blob elem ((nt*32+kc)*64+lane)*8+j  <->  n=nt*16+(lane&15), k=kc*32+(lane>>4)*8+j
__global__ __launch_bounds__(256) void shuffle_w(const float* __restrict__ src,
                                                 bf16* __restrict__ dst, int ngroups) {
  int g = blockIdx.x * 256 + threadIdx.x;
  if (g >= ngroups) return;
  int lane = g & 63, kc = (g >> 6) & 31, nt = g >> 11;
  int n = nt * 16 + (lane & 15);
  int k = kc * 32 + ((lane >> 4) << 3);
  const float* s = src + (size_t)n * HDIM + k;
  s8v v;
#pragma unroll
  for (int j = 0; j < 8; ++j) v[j] = f2bs(s[j]);
  *(s8v*)((short*)dst + (size_t)g * 8) = v;
}

// ====== one-time fp32 tile GEMM: C = [relu](A@W^T + bias [+bias2 for n<lim]) ======
struct GemmArgs {
  const float* A; const float* W; const float* bias; const float* bias2;
  float* C; int ldc; int K; int reluA; int reluC; int b2lim;
};
#define LDP 68
__global__ __launch_bounds__(256) void gemm_bt(GemmArgs g) {
  __shared__ float As[16][LDP];
  __shared__ float Ws[16][LDP];
  const int tid = threadIdx.x;
  const int tx = tid & 15, ty = tid >> 4;
  const int m0 = blockIdx.y * 64, n0 = blockIdx.x * 64;
  float acc[4][4] = {{0.f, 0.f, 0.f, 0.f}};
  const int K = g.K;
  for (int kb = 0; kb < K / 16; ++kb) {
    const int k0 = kb * 16;
#pragma unroll
    for (int i = 0; i < 4; ++i) {
      int idx = tid + i * 256;
      int ml = idx >> 4, kl = idx & 15;
      float a = g.A[(size_t)(m0 + ml) * K + k0 + kl];
      if (g.reluA) a = fmaxf(a, 0.f);
      As[kl][ml] = a;
      Ws[kl][ml] = g.W[(size_t)(n0 + ml) * K + k0 + kl];
    }
    __syncthreads();
#pragma unroll
    for (int k = 0; k < 16; ++k) {
      float4 av = *(const float4*)&As[k][ty * 4];
      float4 wv = *(const float4*)&Ws[k][tx * 4];
      float a[4] = {av.x, av.y, av.z, av.w};
      float w[4] = {wv.x, wv.y, wv.z, wv.w};
#pragma unroll
      for (int i = 0; i < 4; ++i)
#pragma unroll
        for (int j = 0; j < 4; ++j)
          acc[i][j] = fmaf(a[i], w[j], acc[i][j]);
    }
    __syncthreads();
  }
#pragma unroll
  for (int i = 0; i < 4; ++i) {
    int m = m0 + ty * 4 + i;
#pragma unroll
    for (int j = 0; j < 4; ++j) {
      int n = n0 + tx * 4 + j;
      float v = acc[i][j] + g.bias[n];
      if (g.bias2 && n < g.b2lim) v += g.bias2[n];
      if (g.reluC) v = fmaxf(v, 0.f);
      g.C[(size_t)m * g.ldc + n] = v;
    }
  }
}

// ====== one-time: [B,H] fp32 -> frag blob (x2) ======
__global__ __launch_bounds__(256) void permute_frag(const float* __restrict__ s,
                                                    bf16* __restrict__ d0,
                                                    bf16* __restrict__ d1) {
  int g = blockIdx.x * 256 + threadIdx.x;      // (B/16)*32*64 groups
  int lane = g & 63, kc = (g >> 6) & 31, mt = g >> 11;
  int m = mt * 16 + (lane & 15), k = kc * 32 + ((lane >> 4) << 3);
  const float* src = s + (size_t)m * HDIM + k;
  s8v v;
#pragma unroll
  for (int j = 0; j < 8; ++j) v[j] = f2bs(src[j]);
  *(s8v*)((short*)d0 + (size_t)g * 8) = v;
  *(s8v*)((short*)d1 + (size_t)g * 8) = v;
}

__global__ __launch_bounds__(256) void copy_h2(const float* __restrict__ s,
                                               float* __restrict__ d0,
                                               float* __restrict__ d1) {
  int i = blockIdx.x * 256 + threadIdx.x;
  float v = s[i]; d0[i] = v; d1[i] = v;
}

__global__ __launch_bounds__(256) void copy_final(const float* __restrict__ h0,
                                                  const float* __restrict__ h1,
                                                  float* __restrict__ out) {
  int i = blockIdx.x * 256 + threadIdx.x;      // 2*B*H
  const int BH = BATCH * HDIM;
  out[i] = (i < BH) ? h0[i] : h1[i - BH];
}

// ====== per-step fused kernel: 336 blocks, ZERO LDS ======
// [0,128)   layer0  t=k     : m64 x n32 tiles
// [128,256) layer1  t=k-1   : m64 x n32 tiles
// [256,272) logits  t=k-2   : m32 x n256, raw logits+bo -> Lg
// [272,336) softmax t=k-3   : 4 rows/block, shfl-only log_softmax -> out
struct StepArgs {
  int k;
  const int* target;
  const float* table;          // [V,3H] relu(emb)@Wih0^T + b_ih0 + b_hh0(r,z)
  const bf16* Whh0;            // frag blobs
  const bf16* Wih1; const bf16* Whh1; const bf16* Wof;
  const float* bhh0n;          // b_hh0 + 2048
  const float* bih1; const float* bhh1; const float* bo;
  const bf16* h0f_in;  bf16* h0f_out;
  const float* h0l_in; float* h0l_out;
  const bf16* h1f_in;  bf16* h1f_out;   // h1f_in = S1[k-2]
  const float* h1l_in; float* h1l_out;
  float* lg_out; const float* lg_in;
  float* out;
};

__global__ __launch_bounds__(256) void step_fused(StepArgs g) {
  const int blk = blockIdx.x;
  const int tid = threadIdx.x;
  const int w = tid >> 6, ln = tid & 63, l15 = ln & 15, quad = ln >> 4;

  if (blk < 128) {
    // ---------- layer 0, t = k ----------
    if (g.k > 255) return;
    const int nsl = blk & 31, msl = blk >> 5;
    const int MT = (msl << 2) + w;             // wave-private m-tile
    const int NT0 = nsl << 1;                  // two n-tiles (shared by waves -> L1)
    const bf16* pA = g.h0f_in + ((size_t)MT << 14) + ln * 8;
    const bf16* pB[2][3];
#pragma unroll
    for (int nt = 0; nt < 2; ++nt)
#pragma unroll
      for (int gg = 0; gg < 3; ++gg)
        pB[nt][gg] = g.Whh0 + ((size_t)((gg << 6) + NT0 + nt) << 14) + ln * 8;

    f4v acc[2][3];
#pragma unroll
    for (int nt = 0; nt < 2; ++nt)
#pragma unroll
      for (int gg = 0; gg < 3; ++gg) acc[nt][gg] = (f4v){0.f, 0.f, 0.f, 0.f};

#pragma unroll 4
    for (int kc = 0; kc < 32; ++kc) {
      s8v A = ld8(pA + (kc << 9));
#pragma unroll
      for (int nt = 0; nt < 2; ++nt)
#pragma unroll
        for (int gg = 0; gg < 3; ++gg)
          acc[nt][gg] = mfma_bf16(A, ld8(pB[nt][gg] + (kc << 9)), acc[nt][gg]);
    }

    const int mbase = (MT << 4) + (quad << 2);
#pragma unroll
    for (int nt = 0; nt < 2; ++nt) {
      const int n = ((NT0 + nt) << 4) + l15;
      const float bhn = g.bhh0n[n];
      const int kc2 = n >> 5, qp = (n >> 3) & 3, jp = n & 7;
      short* fo = (short*)g.h0f_out + (((size_t)((MT << 5) + kc2) << 6) + (qp << 4)) * 8 + jp;
#pragma unroll
      for (int r = 0; r < 4; ++r) {
        const int m = mbase + r;
        const int tok = (g.k == 0) ? 0 : g.target[m * TLEN + g.k - 1];
        const float* trow = g.table + (size_t)tok * H3;
        float rr = sigf(trow[n] + acc[nt][0][r]);
        float zz = sigf(trow[n + 1024] + acc[nt][1][r]);
        float nn = tanhf(trow[n + 2048] + rr * (acc[nt][2][r] + bhn));
        float hv = (1.f - zz) * nn + zz * g.h0l_in[(size_t)m * HDIM + n];
        g.h0l_out[(size_t)m * HDIM + n] = hv;
        fo[(size_t)(m & 15) * 8] = f2bs(hv);
      }
    }
  } else if (blk < 256) {
    // ---------- layer 1, t = k-1 ----------
    if (g.k < 1 || g.k > 256) return;
    const int b1 = blk - 128;
    const int nsl = b1 & 31, msl = b1 >> 5;
    const int MT = (msl << 2) + w;
    const int NT0 = nsl << 1;
    const bf16* pAx = g.h0f_in + ((size_t)MT << 14) + ln * 8;  // x = S0[k-1]
    const bf16* pAh = g.h1f_in + ((size_t)MT << 14) + ln * 8;  // S1[k-2]
    const bf16* pi[2][3];
    const bf16* ph[2][3];
#pragma unroll
    for (int nt = 0; nt < 2; ++nt)
#pragma unroll
      for (int gg = 0; gg < 3; ++gg) {
        size_t off = ((size_t)((gg << 6) + NT0 + nt) << 14) + ln * 8;
        pi[nt][gg] = g.Wih1 + off;
        ph[nt][gg] = g.Whh1 + off;
      }

    f4v ar[2], az[2], ain[2], ahn[2];
#pragma unroll
    for (int nt = 0; nt < 2; ++nt) {
      ar[nt] = (f4v){0.f, 0.f, 0.f, 0.f}; az[nt] = ar[nt];
      ain[nt] = ar[nt]; ahn[nt] = ar[nt];
    }

#pragma unroll 2
    for (int kc = 0; kc < 32; ++kc) {
      s8v Ax = ld8(pAx + (kc << 9));
      s8v Ah = ld8(pAh + (kc << 9));
#pragma unroll
      for (int nt = 0; nt < 2; ++nt) {
        ar[nt] = mfma_bf16(Ax, ld8(pi[nt][0] + (kc << 9)), ar[nt]);
        ar[nt] = mfma_bf16(Ah, ld8(ph[nt][0] + (kc << 9)), ar[nt]);
        az[nt] = mfma_bf16(Ax, ld8(pi[nt][1] + (kc << 9)), az[nt]);
        az[nt] = mfma_bf16(Ah, ld8(ph[nt][1] + (kc << 9)), az[nt]);
        ain[nt] = mfma_bf16(Ax, ld8(pi[nt][2] + (kc << 9)), ain[nt]);
        ahn[nt] = mfma_bf16(Ah, ld8(ph[nt][2] + (kc << 9)), ahn[nt]);
      }
    }

    const int mbase = (MT << 4) + (quad << 2);
#pragma unroll
    for (int nt = 0; nt < 2; ++nt) {
      const int n = ((NT0 + nt) << 4) + l15;
      const float br = g.bih1[n] + g.bhh1[n];
      const float bz = g.bih1[n + 1024] + g.bhh1[n + 1024];
      const float bin = g.bih1[n + 2048], bhn = g.bhh1[n + 2048];
      const int kc2 = n >> 5, qp = (n >> 3) & 3, jp = n & 7;
      short* fo = (short*)g.h1f_out + (((size_t)((MT << 5) + kc2) << 6) + (qp << 4)) * 8 + jp;
#pragma unroll
      for (int r = 0; r < 4; ++r) {
        const int m = mbase + r;
        float rr = sigf(ar[nt][r] + br);
        float zz = sigf(az[nt][r] + bz);
        float nn = tanhf(ain[nt][r] + bin + rr * (ahn[nt][r] + bhn));
        float hv = (1.f - zz) * nn + zz * g.h1l_in[(size_t)m * HDIM + n];
        g.h1l_out[(size_t)m * HDIM + n] = hv;
        fo[(size_t)(m & 15) * 8] = f2bs(hv);
      }
    }
  } else if (blk < 272) {
    // ---------- logits, t = k-2: Lg[m,v] = h1[k-2] @ Wo^T + bo ----------
    if (g.k < 2 || g.k > 257) return;
    const int b2 = blk - 256;
    const int mt2 = b2 >> 1, nh = b2 & 1;
    const int MT = (mt2 << 1) + (w & 1);
    const int NTb = (nh << 4) + ((w >> 1) << 3);
    const bf16* pA = g.h1f_in + ((size_t)MT << 14) + ln * 8;   // S1[k-2]
    f4v acc[8];
#pragma unroll
    for (int u = 0; u < 8; ++u) acc[u] = (f4v){0.f, 0.f, 0.f, 0.f};
#pragma unroll 2
    for (int kc = 0; kc < 32; ++kc) {
      s8v A = ld8(pA + (kc << 9));
#pragma unroll
      for (int u = 0; u < 8; ++u)
        acc[u] = mfma_bf16(A, ld8(g.Wof + ((size_t)(NTb + u) << 14) + (kc << 9) + ln * 8), acc[u]);
    }
#pragma unroll
    for (int u = 0; u < 8; ++u) {
      const int col = ((NTb + u) << 4) + l15;
      const float bov = g.bo[col];
#pragma unroll
      for (int r = 0; r < 4; ++r) {
        const int m = (MT << 4) + (quad << 2) + r;
        g.lg_out[(size_t)m * VDIM + col] = acc[u][r] + bov;
      }
    }
  } else {
    // ---------- softmax, t = k-3 (shfl-only, one wave per row) ----------
    if (g.k < 3) return;
    const int to = g.k - 3;
    const int row = (blk - 272) * 4 + w;
    const float* src = g.lg_in + (size_t)row * VDIM;
    float v[8];
#pragma unroll
    for (int j = 0; j < 8; ++j) v[j] = src[ln + (j << 6)];
    float mx = v[0];
#pragma unroll
    for (int j = 1; j < 8; ++j) mx = fmaxf(mx, v[j]);
#pragma unroll
    for (int o = 1; o < 64; o <<= 1) mx = fmaxf(mx, __shfl_xor(mx, o));
    float sum = 0.f;
#pragma unroll
    for (int j = 0; j < 8; ++j) sum += expf(v[j] - mx);
#pragma unroll
    for (int o = 1; o < 64; o <<= 1) sum += __shfl_xor(sum, o);
    float lse = mx + logf(sum);
    float* orow = g.out + ((size_t)row * TLEN + to) * VDIM;
#pragma unroll
    for (int j = 0; j < 8; ++j) orow[ln + (j << 6)] = v[j] - lse;
  }
}

extern "C" void kernel_launch(void* const* d_in, const int* in_sizes, int n_in,
                              void* d_out, int out_size, void* d_ws, size_t ws_size,
                              hipStream_t stream) {
  const float* fps    = (const float*)d_in[1];
  const int* target   = (const int*)d_in[2];
  const float* emb    = (const float*)d_in[3];
  const float* Wc     = (const float*)d_in[4];
  const float* bc     = (const float*)d_in[5];
  const float* W_ih   = (const float*)d_in[6];   // [2,3H,H]
  const float* W_hh   = (const float*)d_in[7];
  const float* b_ih   = (const float*)d_in[8];
  const float* b_hh   = (const float*)d_in[9];
  const float* Wo     = (const float*)d_in[10];
  const float* bo     = (const float*)d_in[11];
  float* out = (float*)d_out;

  const int BH = BATCH * HDIM;
  const size_t WN = (size_t)H3 * HDIM;

  char* p = (char*)d_ws;
  float* hstd  = (float*)p; p += (size_t)BH * 4;
  float* table = (float*)p; p += (size_t)VDIM * H3 * 4;
  float* H0l[2]; H0l[0] = (float*)p; p += (size_t)BH * 4; H0l[1] = (float*)p; p += (size_t)BH * 4;
  float* H1l[2]; H1l[0] = (float*)p; p += (size_t)BH * 4; H1l[1] = (float*)p; p += (size_t)BH * 4;
  bf16* H0f[2]; H0f[0] = (bf16*)p; p += (size_t)BH * 2; H0f[1] = (bf16*)p; p += (size_t)BH * 2;
  bf16* H1f[2]; H1f[0] = (bf16*)p; p += (size_t)BH * 2; H1f[1] = (bf16*)p; p += (size_t)BH * 2;
  float* Lg[2]; Lg[0] = (float*)p; p += (size_t)BATCH * VDIM * 4; Lg[1] = (float*)p; p += (size_t)BATCH * VDIM * 4;
  bf16* Whh0f = (bf16*)p; p += WN * 2;
  bf16* Wih1f = (bf16*)p; p += WN * 2;
  bf16* Whh1f = (bf16*)p; p += WN * 2;
  bf16* Wof   = (bf16*)p; p += (size_t)VDIM * HDIM * 2;

  // one-time weight shuffles
  {
    int ng3 = (H3 / 16) * 32 * 64;
    shuffle_w<<<ng3 / 256, 256, 0, stream>>>(W_hh, Whh0f, ng3);
    shuffle_w<<<ng3 / 256, 256, 0, stream>>>(W_ih + WN, Wih1f, ng3);
    shuffle_w<<<ng3 / 256, 256, 0, stream>>>(W_hh + WN, Whh1f, ng3);
    int ngv = (VDIM / 16) * 32 * 64;
    shuffle_w<<<ngv / 256, 256, 0, stream>>>(Wo, Wof, ngv);
  }
  // init hidden: hstd = relu(fps @ Wc^T + bc)
  {
    GemmArgs a; a.A = fps; a.W = Wc; a.bias = bc; a.bias2 = nullptr;
    a.C = hstd; a.ldc = HDIM; a.K = FPDIM; a.reluA = 0; a.reluC = 1; a.b2lim = 0;
    gemm_bt<<<dim3(HDIM / 64, BATCH / 64), 256, 0, stream>>>(a);
  }
  // gi0 table = relu(emb) @ Wih0^T + b_ih0 + b_hh0 (r,z only)
  {
    GemmArgs a; a.A = emb; a.W = W_ih; a.bias = b_ih; a.bias2 = b_hh;
    a.C = table; a.ldc = H3; a.K = HDIM; a.reluA = 1; a.reluC = 0; a.b2lim = 2048;
    gemm_bt<<<dim3(H3 / 64, VDIM / 64), 256, 0, stream>>>(a);
  }
  copy_h2<<<BH / 256, 256, 0, stream>>>(hstd, H0l[0], H1l[0]);
  permute_frag<<<(BATCH / 16) * 32 * 64 / 256, 256, 0, stream>>>(hstd, H0f[0], H1f[0]);

  // pipelined loop: launch k = layer0(k) | layer1(k-1) | logits(k-2) | softmax(k-3)
  for (int k = 0; k <= TLEN + 2; ++k) {
    StepArgs s;
    s.k = k; s.target = target; s.table = table;
    s.Whh0 = Whh0f; s.Wih1 = Wih1f; s.Whh1 = Whh1f; s.Wof = Wof;
    s.bhh0n = b_hh + 2048;
    s.bih1 = b_ih + H3; s.bhh1 = b_hh + H3; s.bo = bo;
    s.h0f_in = H0f[k & 1];        s.h0f_out = H0f[(k + 1) & 1];
    s.h0l_in = H0l[k & 1];        s.h0l_out = H0l[(k + 1) & 1];
    s.h1f_in = H1f[(k + 1) & 1];  s.h1f_out = H1f[k & 1];
    s.h1l_in = H1l[(k + 1) & 1];  s.h1l_out = H1l[k & 1];
    s.lg_out = Lg[k & 1];         s.lg_in = Lg[(k + 1) & 1];
    s.out = out;
    step_fused<<<336, 256, 0, stream>>>(s);
  }

  // h_final (S0[255] and S1[255] both land in parity-0 buffers)
  copy_final<<<2 * BH / 256, 256, 0, stream>>>(H0l[0], H1l[0],
                                               out + (size_t)BATCH * TLEN * VDIM);
}